// Round 1
// baseline (373.000 us; speedup 1.0000x reference)
//
#include <hip/hip_runtime.h>

// Correlation layer: B=4 C=256 H=64 W=96, MAX_DISP=20 STRIDE2=2 -> 21x21 displacements.
// out[b, dy*21+dx, y, x] = (1/C) * sum_c in1[b,c,y,x] * in2[b,c,y+2(dy-10), x+2(dx-10)]
// (in2 out-of-bounds treated as zero).

#define BB 4
#define CC 256
#define HH 64
#define WW 96
#define RADD 10
#define ND 21          // displacements per axis
#define KC 8           // channels staged per LDS round
#define LW 136         // staged row width: cols -20 .. 115

__global__ __launch_bounds__(128)
void Correlation_68367289417895_kernel(const float* __restrict__ in1,
                                       const float* __restrict__ in2,
                                       float* __restrict__ out) {
    const int bid = blockIdx.x;              // ((b*H + y)*ND + dyp)
    const int dyp = bid % ND;
    const int tmp = bid / ND;
    const int y   = tmp % HH;
    const int b   = tmp / HH;
    const int tid = threadIdx.x;
    const int x   = tid;                     // 0..127, compute-valid if < 96

    const int y2 = y + 2 * (dyp - RADD);
    const bool rowvalid = (y2 >= 0 && y2 < HH);

    __shared__ float lds[KC][LW];

    float acc[ND];
#pragma unroll
    for (int k = 0; k < ND; ++k) acc[k] = 0.0f;

    if (rowvalid) {
        const float* p1 = in1 + ((size_t)(b * CC) * HH + y)  * WW;  // + c*H*W + x
        const float* p2 = in2 + ((size_t)(b * CC) * HH + y2) * WW;  // + c*H*W + col

        for (int c0 = 0; c0 < CC; c0 += KC) {
            __syncthreads();
            // stage KC channels of the in2 row (cols -20..115, zero-padded) into LDS
            for (int i = tid; i < KC * LW; i += 128) {
                const int cc  = i / LW;
                const int col = (i % LW) - 20;
                float v = 0.0f;
                if (col >= 0 && col < WW) v = p2[(size_t)(c0 + cc) * HH * WW + col];
                lds[cc][i % LW] = v;
            }
            __syncthreads();

            if (x < WW) {
#pragma unroll
                for (int cc = 0; cc < KC; ++cc) {
                    const float a = p1[(size_t)(c0 + cc) * HH * WW + x];
#pragma unroll
                    for (int k = 0; k < ND; ++k) {
                        // in2 col = x + 2*(k-10); lds col j holds in2 col j-20 -> index x+2k
                        acc[k] += a * lds[cc][x + 2 * k];
                    }
                }
            }
        }
    }

    if (x < WW) {
        float* po = out + (((size_t)b * (ND * ND) + (size_t)dyp * ND) * HH + y) * WW + x;
        const float scale = 1.0f / (float)CC;
#pragma unroll
        for (int k = 0; k < ND; ++k) {
            po[(size_t)k * HH * WW] = rowvalid ? acc[k] * scale : 0.0f;
        }
    }
}

extern "C" void kernel_launch(void* const* d_in, const int* in_sizes, int n_in,
                              void* d_out, int out_size, void* d_ws, size_t ws_size,
                              hipStream_t stream) {
    const float* in1 = (const float*)d_in[0];
    const float* in2 = (const float*)d_in[1];
    float* out = (float*)d_out;

    const int nblocks = BB * HH * ND;  // 4*64*21 = 5376
    Correlation_68367289417895_kernel<<<dim3(nblocks), dim3(128), 0, stream>>>(in1, in2, out);
}